// Round 11
// baseline (426.558 us; speedup 1.0000x reference)
//
#include <hip/hip_runtime.h>

// ---------------------------------------------------------------------------
// GIN encoder, fp16 feature path + MFMA, fused per-layer kernel (512 thr).
// ROUND-11 = ROUND-10 ABLATION (compile-fixed: __builtin_nontemporal_load
// needs ext_vector_type, not HIP uint4 class). 4 layer dispatches run 4
// GATHER variants (layers homogeneous; per-dispatch dur_us = within-round A/B):
//   V0 (layer 0): round-9 baseline — 64-lane uint gather, 2 rows in flight.
//   V1 (layer 1): wide-lane gather — 16 lanes x 16B per row, 4 edges/pass
//                 (4x fewer VMEM instructions), idx via __shfl.
//   V2 (layer 2): V1 + unroll-2 (8 edges in flight).
//   V3 (layer 3): V1 + nontemporal loads (L1 bypass test).
// Rest of structure validated rounds 5-9.
// ---------------------------------------------------------------------------

typedef __attribute__((ext_vector_type(8))) _Float16 f16x8;
typedef __attribute__((ext_vector_type(4))) float f32x4;
typedef __attribute__((ext_vector_type(4))) unsigned int u32x4;

static __device__ __forceinline__ float h2f(unsigned short u) {
  return (float)__builtin_bit_cast(_Float16, u);
}
static __device__ __forceinline__ unsigned short f2h(float f) {
  return __builtin_bit_cast(unsigned short, (_Float16)f);
}
static __device__ __forceinline__ float lo16(unsigned int v) { return h2f((unsigned short)(v & 0xffffu)); }
static __device__ __forceinline__ float hi16(unsigned int v) { return h2f((unsigned short)(v >> 16)); }

#define NB 16     // src bins per row
#define SHIFT 12  // src bin = src >> SHIFT

// ---- CSR build (bins = dst*NB + (src>>SHIFT)) ----
__global__ __launch_bounds__(256) void hist_kernel(const int* __restrict__ src,
                                                   const int* __restrict__ dst,
                                                   int* __restrict__ counts, int E) {
  int e = blockIdx.x * 256 + threadIdx.x;
  if (e < E) {
    int s = src[e], d = dst[e];
    atomicAdd(&counts[d * NB + (s >> SHIFT)], 1);
  }
}

__global__ __launch_bounds__(1024) void scan1_kernel(const int* __restrict__ counts,
                                                     int* __restrict__ incl,
                                                     int* __restrict__ bsums, int n) {
  __shared__ int buf[2][1024];
  int t = threadIdx.x;
  int i = blockIdx.x * 1024 + t;
  buf[0][t] = (i < n) ? counts[i] : 0;
  __syncthreads();
  int cur = 0;
  for (int off = 1; off < 1024; off <<= 1) {
    buf[cur ^ 1][t] = buf[cur][t] + ((t >= off) ? buf[cur][t - off] : 0);
    __syncthreads();
    cur ^= 1;
  }
  if (i < n) incl[i] = buf[cur][t];
  if (t == 1023) bsums[blockIdx.x] = buf[cur][1023];
}

__global__ __launch_bounds__(1024) void scan2_kernel(int* __restrict__ bsums, int nb) {
  __shared__ int buf[2][1024];
  int t = threadIdx.x;
  int v = (t < nb) ? bsums[t] : 0;
  buf[0][t] = v;
  __syncthreads();
  int cur = 0;
  for (int off = 1; off < 1024; off <<= 1) {
    buf[cur ^ 1][t] = buf[cur][t] + ((t >= off) ? buf[cur][t - off] : 0);
    __syncthreads();
    cur ^= 1;
  }
  if (t < nb) bsums[t] = buf[cur][t] - v;  // exclusive
}

__global__ __launch_bounds__(256) void scan3_kernel(const int* __restrict__ counts,
                                                    const int* __restrict__ incl,
                                                    const int* __restrict__ bsums,
                                                    int* __restrict__ offsets,
                                                    int* __restrict__ cursor, int n) {
  int i = blockIdx.x * 256 + threadIdx.x;
  if (i < n) {
    int total = bsums[i >> 10] + incl[i];
    offsets[i + 1] = total;
    cursor[i] = total - counts[i];
  }
  if (i == 0) offsets[0] = 0;
}

__global__ __launch_bounds__(256) void fill_kernel(const int* __restrict__ src,
                                                   const int* __restrict__ dst,
                                                   int* cursor, int* __restrict__ srcs, int E) {
  int e = blockIdx.x * 256 + threadIdx.x;
  if (e < E) {
    int s = src[e], d = dst[e];
    int p = atomicAdd(&cursor[d * NB + (s >> SHIFT)], 1);
    __builtin_nontemporal_store(s, &srcs[p]);
  }
}

// ---- prep: x -> fp16 row-major (uint-packed); zero counts; init affine ----
__global__ __launch_bounds__(256) void prep_kernel(const float* __restrict__ x,
                                                   unsigned int* __restrict__ h,
                                                   int* __restrict__ counts,
                                                   float* __restrict__ scale,
                                                   float* __restrict__ shift, int M) {
  int stride = gridDim.x * 256;
  int tid = blockIdx.x * 256 + threadIdx.x;
  const float2* x2 = (const float2*)x;
  int total = M * 64;
  for (int i = tid; i < total; i += stride) {
    float2 v = x2[i];
    h[i] = (unsigned int)f2h(v.x) | ((unsigned int)f2h(v.y) << 16);
  }
  for (int i = tid; i < M * NB; i += stride) counts[i] = 0;
  if (tid < 128) { scale[tid] = 1.f; shift[tid] = 0.f; }
}

// WT[m][n][k] = f16(W_m[k][n])
__global__ __launch_bounds__(256) void prep_w_kernel(const float* __restrict__ W1,
                                                     const float* __restrict__ W2,
                                                     unsigned short* __restrict__ WT, int total) {
  int idx = blockIdx.x * 256 + threadIdx.x;
  if (idx >= total) return;
  int m = idx >> 14;
  int rem = idx & 16383;
  int n = rem >> 7, k = rem & 127;
  const float* W = ((m & 1) == 0) ? (W1 + (size_t)(m >> 1) * 16384)
                                  : (W2 + (size_t)(m >> 1) * 16384);
  WT[idx] = f2h(W[k * 128 + n]);
}

// ---- fused layer kernel, templated gather variant ----
template <int V>
__global__ __launch_bounds__(512, 8) void layer_kernel(
    const unsigned int* __restrict__ Hin,  // M x 64 uints (fp16x2, row-major)
    const int* __restrict__ offsets,       // M*NB + 1
    const int* __restrict__ srcs,
    const float* __restrict__ scale, const float* __restrict__ shift,
    const unsigned short* __restrict__ WT1, const float* __restrict__ b1,
    const unsigned short* __restrict__ WT2, const float* __restrict__ b2,
    unsigned short* __restrict__ Hout,  // M x 128 fp16 row-major
    float* __restrict__ pstat, int M) {
  __shared__ unsigned short sT[32 * 128];
  __shared__ float s_sum[128], s_sq[128];
  int t = threadIdx.x;
  if (t < 128) { s_sum[t] = 0.f; s_sq[t] = 0.f; }
  int wave = t >> 6, lane = t & 63;
  int row0 = blockIdx.x * 32;
  char* sTb = (char*)sT;

  if constexpr (V == 0) {
    // ---- V0: round-9 baseline gather (2 rows in flight, unroll-4) ----
    float sc0 = scale[2 * lane], sc1 = scale[2 * lane + 1];
    float sh0 = shift[2 * lane], sh1 = shift[2 * lane + 1];
    for (int i = 0; i < 4; i += 2) {
      int rA = row0 + wave * 4 + i;
      int rB = rA + 1;
      float axA = 0.f, ayA = 0.f, axB = 0.f, ayB = 0.f;
      int eA = 0, eA1 = 0, eB = 0, eB1 = 0;
      if (rA < M) {
        eA = offsets[rA * NB]; eA1 = offsets[rA * NB + NB];
        unsigned int s = Hin[(size_t)rA * 64 + lane];
        axA = lo16(s); ayA = hi16(s);
      }
      if (rB < M) {
        eB = offsets[rB * NB]; eB1 = offsets[rB * NB + NB];
        unsigned int s = Hin[(size_t)rB * 64 + lane];
        axB = lo16(s); ayB = hi16(s);
      }
      int dA = eA1 - eA, dB = eB1 - eB;
      while (eA + 4 <= eA1 && eB + 4 <= eB1) {
        int a0 = srcs[eA], a1 = srcs[eA + 1], a2 = srcs[eA + 2], a3 = srcs[eA + 3];
        int c0 = srcs[eB], c1 = srcs[eB + 1], c2 = srcs[eB + 2], c3 = srcs[eB + 3];
        unsigned int vA0 = Hin[(size_t)a0 * 64 + lane];
        unsigned int vA1 = Hin[(size_t)a1 * 64 + lane];
        unsigned int vA2 = Hin[(size_t)a2 * 64 + lane];
        unsigned int vA3 = Hin[(size_t)a3 * 64 + lane];
        unsigned int vB0 = Hin[(size_t)c0 * 64 + lane];
        unsigned int vB1 = Hin[(size_t)c1 * 64 + lane];
        unsigned int vB2 = Hin[(size_t)c2 * 64 + lane];
        unsigned int vB3 = Hin[(size_t)c3 * 64 + lane];
        axA += lo16(vA0) + lo16(vA1) + lo16(vA2) + lo16(vA3);
        ayA += hi16(vA0) + hi16(vA1) + hi16(vA2) + hi16(vA3);
        axB += lo16(vB0) + lo16(vB1) + lo16(vB2) + lo16(vB3);
        ayB += hi16(vB0) + hi16(vB1) + hi16(vB2) + hi16(vB3);
        eA += 4; eB += 4;
      }
      while (eA + 4 <= eA1) {
        int a0 = srcs[eA], a1 = srcs[eA + 1], a2 = srcs[eA + 2], a3 = srcs[eA + 3];
        unsigned int v0 = Hin[(size_t)a0 * 64 + lane];
        unsigned int v1 = Hin[(size_t)a1 * 64 + lane];
        unsigned int v2 = Hin[(size_t)a2 * 64 + lane];
        unsigned int v3 = Hin[(size_t)a3 * 64 + lane];
        axA += lo16(v0) + lo16(v1) + lo16(v2) + lo16(v3);
        ayA += hi16(v0) + hi16(v1) + hi16(v2) + hi16(v3);
        eA += 4;
      }
      while (eB + 4 <= eB1) {
        int c0 = srcs[eB], c1 = srcs[eB + 1], c2 = srcs[eB + 2], c3 = srcs[eB + 3];
        unsigned int v0 = Hin[(size_t)c0 * 64 + lane];
        unsigned int v1 = Hin[(size_t)c1 * 64 + lane];
        unsigned int v2 = Hin[(size_t)c2 * 64 + lane];
        unsigned int v3 = Hin[(size_t)c3 * 64 + lane];
        axB += lo16(v0) + lo16(v1) + lo16(v2) + lo16(v3);
        ayB += hi16(v0) + hi16(v1) + hi16(v2) + hi16(v3);
        eB += 4;
      }
      for (; eA < eA1; ++eA) {
        unsigned int v = Hin[(size_t)srcs[eA] * 64 + lane];
        axA += lo16(v); ayA += hi16(v);
      }
      for (; eB < eB1; ++eB) {
        unsigned int v = Hin[(size_t)srcs[eB] * 64 + lane];
        axB += lo16(v); ayB += hi16(v);
      }
      int rlA = wave * 4 + i, rlB = rlA + 1;
      float dA1 = (float)(dA + 1), dB1 = (float)(dB + 1);
      unsigned int oA = (unsigned int)f2h(axA * sc0 + dA1 * sh0) |
                        ((unsigned int)f2h(ayA * sc1 + dA1 * sh1) << 16);
      unsigned int oB = (unsigned int)f2h(axB * sc0 + dB1 * sh0) |
                        ((unsigned int)f2h(ayB * sc1 + dB1 * sh1) << 16);
      *(unsigned int*)(sTb + rlA * 256 + ((lane * 4) ^ ((rlA & 7) << 4))) = (rA < M) ? oA : 0u;
      *(unsigned int*)(sTb + rlB * 256 + ((lane * 4) ^ ((rlB & 7) << 4))) = (rB < M) ? oB : 0u;
    }
  } else {
    // ---- V1/V2/V3: wide-lane gather: 16 lanes x 16B per row, 4 edges/pass ----
    int sub = lane >> 4, li = lane & 15;
    float sc8[8], sh8[8];
#pragma unroll
    for (int j = 0; j < 8; ++j) { sc8[j] = scale[li * 8 + j]; sh8[j] = shift[li * 8 + j]; }
    for (int i = 0; i < 4; ++i) {
      int r = row0 + wave * 4 + i;
      int rl_ = wave * 4 + i;
      if (r < M) {
        int e0 = offsets[r * NB], e1 = offsets[r * NB + NB];
        float accf[8];
        {
          u32x4 self = (u32x4){0u, 0u, 0u, 0u};
          if (sub == 0) self = *(const u32x4*)(Hin + (size_t)r * 64 + li * 4);
          accf[0] = lo16(self.x); accf[1] = hi16(self.x);
          accf[2] = lo16(self.y); accf[3] = hi16(self.y);
          accf[4] = lo16(self.z); accf[5] = hi16(self.z);
          accf[6] = lo16(self.w); accf[7] = hi16(self.w);
        }
        for (int base = e0; base < e1; base += 64) {
          int cnt = min(64, e1 - base);
          int idxl = (base + lane < e1) ? srcs[base + lane] : 0;
          int np = (cnt + 3) >> 2;
          if constexpr (V == 2) {
            for (int p = 0; p < np; p += 2) {
              int elA = 4 * p + sub, elB = elA + 4;
              int sA = __shfl(idxl, elA);
              int sB = __shfl(idxl, elB & 63);
              bool mA = elA < cnt, mB = elB < cnt;
              u32x4 vA = (u32x4){0u, 0u, 0u, 0u}, vB = (u32x4){0u, 0u, 0u, 0u};
              if (mA) vA = *(const u32x4*)(Hin + (size_t)sA * 64 + li * 4);
              if (mB) vB = *(const u32x4*)(Hin + (size_t)sB * 64 + li * 4);
              accf[0] += lo16(vA.x) + lo16(vB.x); accf[1] += hi16(vA.x) + hi16(vB.x);
              accf[2] += lo16(vA.y) + lo16(vB.y); accf[3] += hi16(vA.y) + hi16(vB.y);
              accf[4] += lo16(vA.z) + lo16(vB.z); accf[5] += hi16(vA.z) + hi16(vB.z);
              accf[6] += lo16(vA.w) + lo16(vB.w); accf[7] += hi16(vA.w) + hi16(vB.w);
            }
          } else {
            for (int p = 0; p < np; ++p) {
              int el = 4 * p + sub;
              int sidx = __shfl(idxl, el);
              if (el < cnt) {
                u32x4 v;
                if constexpr (V == 3) {
                  v = __builtin_nontemporal_load((const u32x4*)(Hin + (size_t)sidx * 64 + li * 4));
                } else {
                  v = *(const u32x4*)(Hin + (size_t)sidx * 64 + li * 4);
                }
                accf[0] += lo16(v.x); accf[1] += hi16(v.x);
                accf[2] += lo16(v.y); accf[3] += hi16(v.y);
                accf[4] += lo16(v.z); accf[5] += hi16(v.z);
                accf[6] += lo16(v.w); accf[7] += hi16(v.w);
              }
            }
          }
        }
        // reduce across the 4 subgroups (lanes ^16, ^32)
#pragma unroll
        for (int j = 0; j < 8; ++j) {
          accf[j] += __shfl_xor(accf[j], 16);
          accf[j] += __shfl_xor(accf[j], 32);
        }
        if (sub == 0) {
          float deg1 = (float)(e1 - e0 + 1);
          unsigned int u0 = (unsigned int)f2h(accf[0] * sc8[0] + deg1 * sh8[0]) |
                            ((unsigned int)f2h(accf[1] * sc8[1] + deg1 * sh8[1]) << 16);
          unsigned int u1 = (unsigned int)f2h(accf[2] * sc8[2] + deg1 * sh8[2]) |
                            ((unsigned int)f2h(accf[3] * sc8[3] + deg1 * sh8[3]) << 16);
          unsigned int u2 = (unsigned int)f2h(accf[4] * sc8[4] + deg1 * sh8[4]) |
                            ((unsigned int)f2h(accf[5] * sc8[5] + deg1 * sh8[5]) << 16);
          unsigned int u3 = (unsigned int)f2h(accf[6] * sc8[6] + deg1 * sh8[6]) |
                            ((unsigned int)f2h(accf[7] * sc8[7] + deg1 * sh8[7]) << 16);
          *(u32x4*)(sTb + rl_ * 256 + ((li * 16) ^ ((rl_ & 7) << 4))) = (u32x4){u0, u1, u2, u3};
        }
      } else if (sub == 0) {
        *(u32x4*)(sTb + rl_ * 256 + ((li * 16) ^ ((rl_ & 7) << 4))) = (u32x4){0u, 0u, 0u, 0u};
      }
    }
  }
  __syncthreads();

  // ---- 8-way wave split: wr = row half (16 rows), wc = col quarter (32) ----
  int wr = wave & 1, wc = wave >> 1;
  int lrow = lane & 15, hi = lane >> 4;
  int lk = hi * 8;
  int rl = wr * 16 + lrow;

  // GEMM1
  f16x8 af[4];
#pragma unroll
  for (int ks = 0; ks < 4; ++ks)
    af[ks] = *(const f16x8*)(sTb + rl * 256 + ((ks * 64 + hi * 16) ^ ((rl & 7) << 4)));
  f32x4 acc[2];
#pragma unroll
  for (int n = 0; n < 2; ++n) acc[n] = (f32x4){0.f, 0.f, 0.f, 0.f};
#pragma unroll
  for (int ks = 0; ks < 4; ++ks) {
    f16x8 bf[2];
#pragma unroll
    for (int n = 0; n < 2; ++n)
      bf[n] = *(const f16x8*)(WT1 + (size_t)(wc * 32 + n * 16 + lrow) * 128 + ks * 32 + lk);
#pragma unroll
    for (int n = 0; n < 2; ++n)
      acc[n] = __builtin_amdgcn_mfma_f32_16x16x32_f16(af[ks], bf[n], acc[n], 0, 0, 0);
  }
  __syncthreads();

  // epilogue1: bias+ReLU -> same LDS tile (swizzled)
#pragma unroll
  for (int n = 0; n < 2; ++n) {
    int col = wc * 32 + n * 16 + lrow;
    float bia = b1[col];
#pragma unroll
    for (int r = 0; r < 4; ++r) {
      int rlw = wr * 16 + hi * 4 + r;
      float v = fmaxf(acc[n][r] + bia, 0.f);
      *(unsigned short*)(sTb + rlw * 256 + ((col * 2) ^ ((rlw & 7) << 4))) = f2h(v);
    }
  }
  __syncthreads();

  // GEMM2
#pragma unroll
  for (int ks = 0; ks < 4; ++ks)
    af[ks] = *(const f16x8*)(sTb + rl * 256 + ((ks * 64 + hi * 16) ^ ((rl & 7) << 4)));
#pragma unroll
  for (int n = 0; n < 2; ++n) acc[n] = (f32x4){0.f, 0.f, 0.f, 0.f};
#pragma unroll
  for (int ks = 0; ks < 4; ++ks) {
    f16x8 bf[2];
#pragma unroll
    for (int n = 0; n < 2; ++n)
      bf[n] = *(const f16x8*)(WT2 + (size_t)(wc * 32 + n * 16 + lrow) * 128 + ks * 32 + lk);
#pragma unroll
    for (int n = 0; n < 2; ++n)
      acc[n] = __builtin_amdgcn_mfma_f32_16x16x32_f16(af[ks], bf[n], acc[n], 0, 0, 0);
  }

  // epilogue2: bias+ReLU -> Hout + per-block column stats (LDS atomics only)
  int rbase = row0 + wr * 16 + hi * 4;
#pragma unroll
  for (int n = 0; n < 2; ++n) {
    int col = wc * 32 + n * 16 + lrow;
    float bia = b2[col];
    float cs = 0.f, cq = 0.f;
#pragma unroll
    for (int r = 0; r < 4; ++r) {
      int rr = rbase + r;
      float v = fmaxf(acc[n][r] + bia, 0.f);
      if (rr < M) {
        Hout[(size_t)rr * 128 + col] = f2h(v);
        cs += v;
        cq += v * v;
      }
    }
    cs += __shfl_xor(cs, 16); cs += __shfl_xor(cs, 32);
    cq += __shfl_xor(cq, 16); cq += __shfl_xor(cq, 32);
    if (hi == 0) {
      atomicAdd(&s_sum[col], cs);
      atomicAdd(&s_sq[col], cq);
    }
  }
  __syncthreads();
  if (t < 128) {
    float* p = pstat + (size_t)blockIdx.x * 256;
    p[t] = s_sum[t];
    p[t + 128] = s_sq[t];
  }
}

// reduce per-block partials -> scale/shift for the next layer
__global__ __launch_bounds__(256) void bn_stats_kernel(const float* __restrict__ pstat, int nb,
                                                       const float* __restrict__ gamma,
                                                       const float* __restrict__ beta,
                                                       float* __restrict__ scale,
                                                       float* __restrict__ shift, float invM) {
  int c = blockIdx.x;
  int t = threadIdx.x;
  float s = 0.f, q = 0.f;
  for (int b = t; b < nb; b += 256) {
    const float* p = pstat + (size_t)b * 256;
    s += p[c];
    q += p[c + 128];
  }
#pragma unroll
  for (int off = 1; off < 64; off <<= 1) {
    s += __shfl_xor(s, off);
    q += __shfl_xor(q, off);
  }
  __shared__ float rs[4], rq[4];
  if ((t & 63) == 0) { rs[t >> 6] = s; rq[t >> 6] = q; }
  __syncthreads();
  if (t == 0) {
    float S = rs[0] + rs[1] + rs[2] + rs[3];
    float Q = rq[0] + rq[1] + rq[2] + rq[3];
    float mean = S * invM;
    float var = fmaxf(Q * invM - mean * mean, 0.f);
    float sc = gamma[c] * rsqrtf(var + 1e-5f);
    scale[c] = sc;
    shift[c] = beta[c] - mean * sc;
  }
}

// ---- fused pool (last layer BN) + projection ----
__global__ __launch_bounds__(256) void pool_proj_kernel(const unsigned int* __restrict__ H,
                                                        const int* __restrict__ batch,
                                                        const float* __restrict__ scale,
                                                        const float* __restrict__ shift,
                                                        const float* __restrict__ Wp,
                                                        const float* __restrict__ bp,
                                                        float* __restrict__ out, int M) {
  int gid = blockIdx.x;
  int lo = 0, hi = M;
  while (lo < hi) { int mid = (lo + hi) >> 1; if (batch[mid] < gid) lo = mid + 1; else hi = mid; }
  int s = lo;
  lo = 0; hi = M;
  while (lo < hi) { int mid = (lo + hi) >> 1; if (batch[mid] < gid + 1) lo = mid + 1; else hi = mid; }
  int e = lo;
  int t = threadIdx.x;
  int cp = t & 63, rs_ = t >> 6;
  float ax = 0.f, ay = 0.f;
  for (int r = s + rs_; r < e; r += 4) {
    unsigned int v = H[(size_t)r * 64 + cp];
    ax += lo16(v);
    ay += hi16(v);
  }
  __shared__ float redx[256], redy[256];
  __shared__ float g[128];
  redx[t] = ax;
  redy[t] = ay;
  __syncthreads();
  if (t < 128) {
    int cpp = t >> 1;
    float sum;
    if (t & 1)
      sum = redy[cpp] + redy[64 + cpp] + redy[128 + cpp] + redy[192 + cpp];
    else
      sum = redx[cpp] + redx[64 + cpp] + redx[128 + cpp] + redx[192 + cpp];
    g[t] = sum * scale[t] + (float)(e - s) * shift[t];
  }
  __syncthreads();
  if (t < 128) {
    float a2 = bp[t];
#pragma unroll 8
    for (int k = 0; k < 128; ++k) a2 = fmaf(g[k], Wp[k * 128 + t], a2);
    out[gid * 128 + t] = fmaxf(a2, 0.f);
  }
}

extern "C" void kernel_launch(void* const* d_in, const int* in_sizes, int n_in,
                              void* d_out, int out_size, void* d_ws, size_t ws_size,
                              hipStream_t stream) {
  const float* x = (const float*)d_in[0];
  const int* ei = (const int*)d_in[1];
  const int* batch = (const int*)d_in[2];
  const float* W1 = (const float*)d_in[3];
  const float* b1 = (const float*)d_in[4];
  const float* W2 = (const float*)d_in[5];
  const float* b2 = (const float*)d_in[6];
  const float* gamma = (const float*)d_in[7];
  const float* beta = (const float*)d_in[8];
  const float* Wp = (const float*)d_in[9];
  const float* bp = (const float*)d_in[10];
  float* out = (float*)d_out;

  int M = in_sizes[0] / 128;
  int E = in_sizes[1] / 2;
  int L = in_sizes[3] / (128 * 128);
  int G = out_size / 128;
  const int* srcp = ei;
  const int* dstp = ei + E;

  char* w = (char*)d_ws;
  auto alloc = [&](size_t bytes) {
    char* p = w;
    w += (bytes + 255) & ~(size_t)255;
    return p;
  };
  int nblk = (M + 31) / 32;
  int MB = M * NB;
  size_t binbytes = (size_t)MB * 4;
  size_t ebytes = (size_t)E * 4;
  unsigned int* bufA = (unsigned int*)alloc((size_t)M * 64 * 4);
  unsigned int* bufB = (unsigned int*)alloc((size_t)M * 64 * 4);
  unsigned short* WT = (unsigned short*)alloc((size_t)L * 2 * 16384 * 2);
  char* regionA = alloc(2 * binbytes > ebytes ? 2 * binbytes : ebytes);
  int* counts = (int*)regionA;
  int* incl = (int*)(regionA + binbytes);
  int* srcs = (int*)regionA;  // aliases counts/incl (dead after scan3)
  int* bsums = (int*)alloc(1024 * 4);
  int* offsets = (int*)alloc(binbytes + 256);
  int* cursor = (int*)alloc(binbytes);
  float* pstat = (float*)alloc((size_t)nblk * 256 * 4);
  float* stats = (float*)alloc(2 * 128 * 4);
  float* scale = stats;
  float* shift = stats + 128;

  int nb1 = (MB + 1023) / 1024;

  prep_kernel<<<2048, 256, 0, stream>>>(x, bufA, counts, scale, shift, M);
  hist_kernel<<<(E + 255) / 256, 256, 0, stream>>>(srcp, dstp, counts, E);
  scan1_kernel<<<nb1, 1024, 0, stream>>>(counts, incl, bsums, MB);
  scan2_kernel<<<1, 1024, 0, stream>>>(bsums, nb1);
  scan3_kernel<<<(MB + 255) / 256, 256, 0, stream>>>(counts, incl, bsums, offsets, cursor, MB);
  fill_kernel<<<(E + 255) / 256, 256, 0, stream>>>(srcp, dstp, cursor, srcs, E);
  prep_w_kernel<<<(L * 2 * 16384 + 255) / 256, 256, 0, stream>>>(W1, W2, WT, L * 2 * 16384);

  float invM = 1.0f / (float)M;
  unsigned int* cur = bufA;
  unsigned int* nxt = bufB;
  for (int l = 0; l < L; ++l) {
    const unsigned short* wt1 = WT + (size_t)(2 * l) * 16384;
    const unsigned short* wt2 = WT + (size_t)(2 * l + 1) * 16384;
    const float* bb1 = b1 + l * 128;
    const float* bb2 = b2 + l * 128;
    unsigned short* ho = (unsigned short*)nxt;
    switch (l & 3) {
      case 0: layer_kernel<0><<<nblk, 512, 0, stream>>>(cur, offsets, srcs, scale, shift, wt1, bb1, wt2, bb2, ho, pstat, M); break;
      case 1: layer_kernel<1><<<nblk, 512, 0, stream>>>(cur, offsets, srcs, scale, shift, wt1, bb1, wt2, bb2, ho, pstat, M); break;
      case 2: layer_kernel<2><<<nblk, 512, 0, stream>>>(cur, offsets, srcs, scale, shift, wt1, bb1, wt2, bb2, ho, pstat, M); break;
      case 3: layer_kernel<3><<<nblk, 512, 0, stream>>>(cur, offsets, srcs, scale, shift, wt1, bb1, wt2, bb2, ho, pstat, M); break;
    }
    bn_stats_kernel<<<128, 256, 0, stream>>>(pstat, nblk, gamma + l * 128, beta + l * 128,
                                             scale, shift, invM);
    unsigned int* tmp = cur; cur = nxt; nxt = tmp;
  }

  pool_proj_kernel<<<G, 256, 0, stream>>>(cur, batch, scale, shift, Wp, bp, out, M);
}

// Round 12
// 396.685 us; speedup vs baseline: 1.0753x; 1.0753x over previous
//
#include <hip/hip_runtime.h>

// ---------------------------------------------------------------------------
// GIN encoder, fp16 feature path + MFMA, fused per-layer kernel (512 thr).
// Gather floor (rounds 6-11 ablations): compulsory per-XCD re-fetch of H
// (~86 MB/layer) at the ~1.25 TB/s random-fill rate => ~70 us/layer. This
// round harvests CSR-build time instead:
//  - 2-pass LDS-staged radix replaces the 50 us write-amplified fill:
//    passA: coarse sort into 98 dst-buckets (LDS bin+rank, 1 atomic/bucket/
//    block, coalesced run writes); passB: fine scatter inside each bucket's
//    16KB L2-hot window (4 blocks/bucket).
//  - NB=1 CSR (src-binning was a null result), scans over 50k not 800k.
//  - ushort srcs (M < 65536), single-variant layer kernel (no co-compile
//    regalloc perturbation).
// Layer kernel structure validated rounds 5-9: gather+prev-BN -> swizzled
// LDS -> GEMM1 -> LDS -> GEMM2 -> Hout + per-block stats; bn_stats reduces;
// last-layer BN folds into pool_proj.
// ---------------------------------------------------------------------------

typedef __attribute__((ext_vector_type(8))) _Float16 f16x8;
typedef __attribute__((ext_vector_type(4))) float f32x4;

static __device__ __forceinline__ float h2f(unsigned short u) {
  return (float)__builtin_bit_cast(_Float16, u);
}
static __device__ __forceinline__ unsigned short f2h(float f) {
  return __builtin_bit_cast(unsigned short, (_Float16)f);
}
static __device__ __forceinline__ float lo16(unsigned int v) { return h2f((unsigned short)(v & 0xffffu)); }
static __device__ __forceinline__ float hi16(unsigned int v) { return h2f((unsigned short)(v >> 16)); }

// ---- CSR build ----
__global__ __launch_bounds__(256) void hist_kernel(const int* __restrict__ dst,
                                                   int* __restrict__ counts, int E) {
  int e = blockIdx.x * 256 + threadIdx.x;
  if (e < E) atomicAdd(&counts[dst[e]], 1);
}

__global__ __launch_bounds__(1024) void scan1_kernel(const int* __restrict__ counts,
                                                     int* __restrict__ incl,
                                                     int* __restrict__ bsums, int n) {
  __shared__ int buf[2][1024];
  int t = threadIdx.x;
  int i = blockIdx.x * 1024 + t;
  buf[0][t] = (i < n) ? counts[i] : 0;
  __syncthreads();
  int cur = 0;
  for (int off = 1; off < 1024; off <<= 1) {
    buf[cur ^ 1][t] = buf[cur][t] + ((t >= off) ? buf[cur][t - off] : 0);
    __syncthreads();
    cur ^= 1;
  }
  if (i < n) incl[i] = buf[cur][t];
  if (t == 1023) bsums[blockIdx.x] = buf[cur][1023];
}

__global__ __launch_bounds__(1024) void scan2_kernel(int* __restrict__ bsums, int nb) {
  __shared__ int buf[2][1024];
  int t = threadIdx.x;
  int v = (t < nb) ? bsums[t] : 0;
  buf[0][t] = v;
  __syncthreads();
  int cur = 0;
  for (int off = 1; off < 1024; off <<= 1) {
    buf[cur ^ 1][t] = buf[cur][t] + ((t >= off) ? buf[cur][t - off] : 0);
    __syncthreads();
    cur ^= 1;
  }
  if (t < nb) bsums[t] = buf[cur][t] - v;  // exclusive
}

// offsets[i+1], cursor[i] = offsets[i] (fine cursor), ccursor[b] = offsets[b*512]
__global__ __launch_bounds__(256) void scan3_kernel(const int* __restrict__ counts,
                                                    const int* __restrict__ incl,
                                                    const int* __restrict__ bsums,
                                                    int* __restrict__ offsets,
                                                    int* __restrict__ cursor,
                                                    int* __restrict__ ccursor, int n) {
  int i = blockIdx.x * 256 + threadIdx.x;
  if (i < n) {
    int total = bsums[i >> 10] + incl[i];
    offsets[i + 1] = total;
    int start = total - counts[i];
    cursor[i] = start;
    if ((i & 511) == 0) ccursor[i >> 9] = start;
  }
  if (i == 0) offsets[0] = 0;
}

// ---- passA: coarse sort edges into 512-row buckets; packed v=(d<<16)|s ----
// bucket(v) = v >> 25 (= d >> 9). One global atomic per (block,bucket);
// LDS rank+reorder so global writes are contiguous runs per bucket.
#define EPB 4096
__global__ __launch_bounds__(256) void sortA_kernel(const int* __restrict__ src,
                                                    const int* __restrict__ dst,
                                                    int* __restrict__ ccursor,
                                                    unsigned int* __restrict__ tmp,
                                                    int E, int CB) {
  __shared__ int cnt[128], pref[128], gbase[128];
  __shared__ int scanbuf[2][128];
  __shared__ unsigned int vals[EPB];
  int t = threadIdx.x;
  int base = blockIdx.x * EPB;
  int nloc = min(EPB, E - base);
  if (t < 128) cnt[t] = 0;
  __syncthreads();

  unsigned int vj[16];
  int rj[16];
#pragma unroll
  for (int j = 0; j < 16; ++j) {
    int e = base + j * 256 + t;
    vj[j] = 0u;
    rj[j] = -1;
    if (e < base + nloc) {
      int s = src[e], d = dst[e];
      unsigned int v = ((unsigned int)d << 16) | (unsigned int)s;
      vj[j] = v;
      rj[j] = atomicAdd(&cnt[v >> 25], 1);
    }
  }
  __syncthreads();
  // exclusive prefix over 128 buckets
  if (t < 128) scanbuf[0][t] = cnt[t];
  __syncthreads();
  int cur = 0;
  for (int off = 1; off < 128; off <<= 1) {
    if (t < 128) scanbuf[cur ^ 1][t] = scanbuf[cur][t] + ((t >= off) ? scanbuf[cur][t - off] : 0);
    __syncthreads();
    cur ^= 1;
  }
  if (t < 128) pref[t] = scanbuf[cur][t] - cnt[t];
  __syncthreads();
  if (t < 128 && t < CB && cnt[t] > 0) gbase[t] = atomicAdd(&ccursor[t], cnt[t]);
  __syncthreads();
  // LDS reorder
#pragma unroll
  for (int j = 0; j < 16; ++j) {
    if (rj[j] >= 0) vals[pref[vj[j] >> 25] + rj[j]] = vj[j];
  }
  __syncthreads();
  // linear write-out: runs per bucket are contiguous in global
  for (int j = t; j < nloc; j += 256) {
    unsigned int v = vals[j];
    int b = v >> 25;
    tmp[gbase[b] + (j - pref[b])] = v;
  }
}

// ---- passB: fine scatter within each bucket's L2-hot window ----
__global__ __launch_bounds__(256) void sortB_kernel(const unsigned int* __restrict__ tmp,
                                                    const int* __restrict__ offsets,
                                                    int* __restrict__ cursor,
                                                    unsigned short* __restrict__ srcs,
                                                    int M) {
  int b = blockIdx.x >> 2, k = blockIdx.x & 3;
  int r0 = b << 9;
  int rEnd = min(r0 + 512, M);
  int e0 = offsets[r0], e1 = offsets[rEnd];
  int n = e1 - e0;
  int start = e0 + (int)(((long long)n * k) >> 2);
  int end = e0 + (int)(((long long)n * (k + 1)) >> 2);
  for (int e = start + threadIdx.x; e < end; e += 256) {
    unsigned int v = tmp[e];
    int d = v >> 16;
    int p = atomicAdd(&cursor[d], 1);
    srcs[p] = (unsigned short)(v & 0xffffu);
  }
}

// ---- prep: x -> fp16 row-major (uint-packed); zero counts; init affine ----
__global__ __launch_bounds__(256) void prep_kernel(const float* __restrict__ x,
                                                   unsigned int* __restrict__ h,
                                                   int* __restrict__ counts,
                                                   float* __restrict__ scale,
                                                   float* __restrict__ shift, int M) {
  int stride = gridDim.x * 256;
  int tid = blockIdx.x * 256 + threadIdx.x;
  const float2* x2 = (const float2*)x;
  int total = M * 64;
  for (int i = tid; i < total; i += stride) {
    float2 v = x2[i];
    h[i] = (unsigned int)f2h(v.x) | ((unsigned int)f2h(v.y) << 16);
  }
  for (int i = tid; i < M; i += stride) counts[i] = 0;
  if (tid < 128) { scale[tid] = 1.f; shift[tid] = 0.f; }
}

// WT[m][n][k] = f16(W_m[k][n])
__global__ __launch_bounds__(256) void prep_w_kernel(const float* __restrict__ W1,
                                                     const float* __restrict__ W2,
                                                     unsigned short* __restrict__ WT, int total) {
  int idx = blockIdx.x * 256 + threadIdx.x;
  if (idx >= total) return;
  int m = idx >> 14;
  int rem = idx & 16383;
  int n = rem >> 7, k = rem & 127;
  const float* W = ((m & 1) == 0) ? (W1 + (size_t)(m >> 1) * 16384)
                                  : (W2 + (size_t)(m >> 1) * 16384);
  WT[idx] = f2h(W[k * 128 + n]);
}

// ---- fused layer: gather+BN -> LDS -> GEMM1 -> LDS -> GEMM2 -> Hout+stats ----
// 32-row tile, 8 waves; each wave gathers 4 rows (2 in flight, unroll-4).
// LDS tile swizzle: fp16 col c of row rl at byte (rl*256 + ((c*2) ^ ((rl&7)<<4))).
// MFMA frag layouts (m89-verified, rounds 3-11).
__global__ __launch_bounds__(512, 8) void layer_kernel(
    const unsigned int* __restrict__ Hin,  // M x 64 uints (fp16x2, row-major)
    const int* __restrict__ offsets,       // M + 1
    const unsigned short* __restrict__ srcs,
    const float* __restrict__ scale, const float* __restrict__ shift,
    const unsigned short* __restrict__ WT1, const float* __restrict__ b1,
    const unsigned short* __restrict__ WT2, const float* __restrict__ b2,
    unsigned short* __restrict__ Hout,  // M x 128 fp16 row-major
    float* __restrict__ pstat, int M) {
  __shared__ unsigned short sT[32 * 128];
  __shared__ float s_sum[128], s_sq[128];
  int t = threadIdx.x;
  if (t < 128) { s_sum[t] = 0.f; s_sq[t] = 0.f; }
  int wave = t >> 6, lane = t & 63;
  int row0 = blockIdx.x * 32;
  char* sTb = (char*)sT;
  float sc0 = scale[2 * lane], sc1 = scale[2 * lane + 1];
  float sh0 = shift[2 * lane], sh1 = shift[2 * lane + 1];

  // ---- phase A: gather + prev-layer BN (2 rows in flight, unroll-4) ----
  for (int i = 0; i < 4; i += 2) {
    int rA = row0 + wave * 4 + i;
    int rB = rA + 1;
    float axA = 0.f, ayA = 0.f, axB = 0.f, ayB = 0.f;
    int eA = 0, eA1 = 0, eB = 0, eB1 = 0;
    if (rA < M) {
      eA = offsets[rA]; eA1 = offsets[rA + 1];
      unsigned int s = Hin[(size_t)rA * 64 + lane];
      axA = lo16(s); ayA = hi16(s);
    }
    if (rB < M) {
      eB = offsets[rB]; eB1 = offsets[rB + 1];
      unsigned int s = Hin[(size_t)rB * 64 + lane];
      axB = lo16(s); ayB = hi16(s);
    }
    int dA = eA1 - eA, dB = eB1 - eB;
    while (eA + 4 <= eA1 && eB + 4 <= eB1) {
      int a0 = srcs[eA], a1 = srcs[eA + 1], a2 = srcs[eA + 2], a3 = srcs[eA + 3];
      int c0 = srcs[eB], c1 = srcs[eB + 1], c2 = srcs[eB + 2], c3 = srcs[eB + 3];
      unsigned int vA0 = Hin[(size_t)a0 * 64 + lane];
      unsigned int vA1 = Hin[(size_t)a1 * 64 + lane];
      unsigned int vA2 = Hin[(size_t)a2 * 64 + lane];
      unsigned int vA3 = Hin[(size_t)a3 * 64 + lane];
      unsigned int vB0 = Hin[(size_t)c0 * 64 + lane];
      unsigned int vB1 = Hin[(size_t)c1 * 64 + lane];
      unsigned int vB2 = Hin[(size_t)c2 * 64 + lane];
      unsigned int vB3 = Hin[(size_t)c3 * 64 + lane];
      axA += lo16(vA0) + lo16(vA1) + lo16(vA2) + lo16(vA3);
      ayA += hi16(vA0) + hi16(vA1) + hi16(vA2) + hi16(vA3);
      axB += lo16(vB0) + lo16(vB1) + lo16(vB2) + lo16(vB3);
      ayB += hi16(vB0) + hi16(vB1) + hi16(vB2) + hi16(vB3);
      eA += 4; eB += 4;
    }
    while (eA + 4 <= eA1) {
      int a0 = srcs[eA], a1 = srcs[eA + 1], a2 = srcs[eA + 2], a3 = srcs[eA + 3];
      unsigned int v0 = Hin[(size_t)a0 * 64 + lane];
      unsigned int v1 = Hin[(size_t)a1 * 64 + lane];
      unsigned int v2 = Hin[(size_t)a2 * 64 + lane];
      unsigned int v3 = Hin[(size_t)a3 * 64 + lane];
      axA += lo16(v0) + lo16(v1) + lo16(v2) + lo16(v3);
      ayA += hi16(v0) + hi16(v1) + hi16(v2) + hi16(v3);
      eA += 4;
    }
    while (eB + 4 <= eB1) {
      int c0 = srcs[eB], c1 = srcs[eB + 1], c2 = srcs[eB + 2], c3 = srcs[eB + 3];
      unsigned int v0 = Hin[(size_t)c0 * 64 + lane];
      unsigned int v1 = Hin[(size_t)c1 * 64 + lane];
      unsigned int v2 = Hin[(size_t)c2 * 64 + lane];
      unsigned int v3 = Hin[(size_t)c3 * 64 + lane];
      axB += lo16(v0) + lo16(v1) + lo16(v2) + lo16(v3);
      ayB += hi16(v0) + hi16(v1) + hi16(v2) + hi16(v3);
      eB += 4;
    }
    for (; eA < eA1; ++eA) {
      unsigned int v = Hin[(size_t)srcs[eA] * 64 + lane];
      axA += lo16(v); ayA += hi16(v);
    }
    for (; eB < eB1; ++eB) {
      unsigned int v = Hin[(size_t)srcs[eB] * 64 + lane];
      axB += lo16(v); ayB += hi16(v);
    }
    int rlA = wave * 4 + i, rlB = rlA + 1;
    float dA1 = (float)(dA + 1), dB1 = (float)(dB + 1);
    unsigned int oA = (unsigned int)f2h(axA * sc0 + dA1 * sh0) |
                      ((unsigned int)f2h(ayA * sc1 + dA1 * sh1) << 16);
    unsigned int oB = (unsigned int)f2h(axB * sc0 + dB1 * sh0) |
                      ((unsigned int)f2h(ayB * sc1 + dB1 * sh1) << 16);
    *(unsigned int*)(sTb + rlA * 256 + ((lane * 4) ^ ((rlA & 7) << 4))) = (rA < M) ? oA : 0u;
    *(unsigned int*)(sTb + rlB * 256 + ((lane * 4) ^ ((rlB & 7) << 4))) = (rB < M) ? oB : 0u;
  }
  __syncthreads();

  // ---- 8-way wave split: wr = row half (16 rows), wc = col quarter (32) ----
  int wr = wave & 1, wc = wave >> 1;
  int lrow = lane & 15, hi = lane >> 4;
  int lk = hi * 8;
  int rl = wr * 16 + lrow;

  // GEMM1
  f16x8 af[4];
#pragma unroll
  for (int ks = 0; ks < 4; ++ks)
    af[ks] = *(const f16x8*)(sTb + rl * 256 + ((ks * 64 + hi * 16) ^ ((rl & 7) << 4)));
  f32x4 acc[2];
#pragma unroll
  for (int n = 0; n < 2; ++n) acc[n] = (f32x4){0.f, 0.f, 0.f, 0.f};
#pragma unroll
  for (int ks = 0; ks < 4; ++ks) {
    f16x8 bf[2];
#pragma unroll
    for (int n = 0; n < 2; ++n)
      bf[n] = *(const f16x8*)(WT1 + (size_t)(wc * 32 + n * 16 + lrow) * 128 + ks * 32 + lk);
#pragma unroll
    for (int n = 0; n < 2; ++n)
      acc[n] = __builtin_amdgcn_mfma_f32_16x16x32_f16(af[ks], bf[n], acc[n], 0, 0, 0);
  }
  __syncthreads();

  // epilogue1: bias+ReLU -> same LDS tile (swizzled)
#pragma unroll
  for (int n = 0; n < 2; ++n) {
    int col = wc * 32 + n * 16 + lrow;
    float bia = b1[col];
#pragma unroll
    for (int r = 0; r < 4; ++r) {
      int rlw = wr * 16 + hi * 4 + r;
      float v = fmaxf(acc[n][r] + bia, 0.f);
      *(unsigned short*)(sTb + rlw * 256 + ((col * 2) ^ ((rlw & 7) << 4))) = f2h(v);
    }
  }
  __syncthreads();

  // GEMM2
#pragma unroll
  for (int ks = 0; ks < 4; ++ks)
    af[ks] = *(const f16x8*)(sTb + rl * 256 + ((ks * 64 + hi * 16) ^ ((rl & 7) << 4)));
#pragma unroll
  for (int n = 0; n < 2; ++n) acc[n] = (f32x4){0.f, 0.f, 0.f, 0.f};
#pragma unroll
  for (int ks = 0; ks < 4; ++ks) {
    f16x8 bf[2];
#pragma unroll
    for (int n = 0; n < 2; ++n)
      bf[n] = *(const f16x8*)(WT2 + (size_t)(wc * 32 + n * 16 + lrow) * 128 + ks * 32 + lk);
#pragma unroll
    for (int n = 0; n < 2; ++n)
      acc[n] = __builtin_amdgcn_mfma_f32_16x16x32_f16(af[ks], bf[n], acc[n], 0, 0, 0);
  }

  // epilogue2: bias+ReLU -> Hout + per-block column stats (LDS atomics only)
  int rbase = row0 + wr * 16 + hi * 4;
#pragma unroll
  for (int n = 0; n < 2; ++n) {
    int col = wc * 32 + n * 16 + lrow;
    float bia = b2[col];
    float cs = 0.f, cq = 0.f;
#pragma unroll
    for (int r = 0; r < 4; ++r) {
      int rr = rbase + r;
      float v = fmaxf(acc[n][r] + bia, 0.f);
      if (rr < M) {
        Hout[(size_t)rr * 128 + col] = f2h(v);
        cs += v;
        cq += v * v;
      }
    }
    cs += __shfl_xor(cs, 16); cs += __shfl_xor(cs, 32);
    cq += __shfl_xor(cq, 16); cq += __shfl_xor(cq, 32);
    if (hi == 0) {
      atomicAdd(&s_sum[col], cs);
      atomicAdd(&s_sq[col], cq);
    }
  }
  __syncthreads();
  if (t < 128) {
    float* p = pstat + (size_t)blockIdx.x * 256;
    p[t] = s_sum[t];
    p[t + 128] = s_sq[t];
  }
}

// reduce per-block partials -> scale/shift for the next layer
__global__ __launch_bounds__(256) void bn_stats_kernel(const float* __restrict__ pstat, int nb,
                                                       const float* __restrict__ gamma,
                                                       const float* __restrict__ beta,
                                                       float* __restrict__ scale,
                                                       float* __restrict__ shift, float invM) {
  int c = blockIdx.x;
  int t = threadIdx.x;
  float s = 0.f, q = 0.f;
  for (int b = t; b < nb; b += 256) {
    const float* p = pstat + (size_t)b * 256;
    s += p[c];
    q += p[c + 128];
  }
#pragma unroll
  for (int off = 1; off < 64; off <<= 1) {
    s += __shfl_xor(s, off);
    q += __shfl_xor(q, off);
  }
  __shared__ float rs[4], rq[4];
  if ((t & 63) == 0) { rs[t >> 6] = s; rq[t >> 6] = q; }
  __syncthreads();
  if (t == 0) {
    float S = rs[0] + rs[1] + rs[2] + rs[3];
    float Q = rq[0] + rq[1] + rq[2] + rq[3];
    float mean = S * invM;
    float var = fmaxf(Q * invM - mean * mean, 0.f);
    float sc = gamma[c] * rsqrtf(var + 1e-5f);
    scale[c] = sc;
    shift[c] = beta[c] - mean * sc;
  }
}

// ---- fused pool (last layer BN) + projection ----
__global__ __launch_bounds__(256) void pool_proj_kernel(const unsigned int* __restrict__ H,
                                                        const int* __restrict__ batch,
                                                        const float* __restrict__ scale,
                                                        const float* __restrict__ shift,
                                                        const float* __restrict__ Wp,
                                                        const float* __restrict__ bp,
                                                        float* __restrict__ out, int M) {
  int gid = blockIdx.x;
  int lo = 0, hi = M;
  while (lo < hi) { int mid = (lo + hi) >> 1; if (batch[mid] < gid) lo = mid + 1; else hi = mid; }
  int s = lo;
  lo = 0; hi = M;
  while (lo < hi) { int mid = (lo + hi) >> 1; if (batch[mid] < gid + 1) lo = mid + 1; else hi = mid; }
  int e = lo;
  int t = threadIdx.x;
  int cp = t & 63, rs_ = t >> 6;
  float ax = 0.f, ay = 0.f;
  for (int r = s + rs_; r < e; r += 4) {
    unsigned int v = H[(size_t)r * 64 + cp];
    ax += lo16(v);
    ay += hi16(v);
  }
  __shared__ float redx[256], redy[256];
  __shared__ float g[128];
  redx[t] = ax;
  redy[t] = ay;
  __syncthreads();
  if (t < 128) {
    int cpp = t >> 1;
    float sum;
    if (t & 1)
      sum = redy[cpp] + redy[64 + cpp] + redy[128 + cpp] + redy[192 + cpp];
    else
      sum = redx[cpp] + redx[64 + cpp] + redx[128 + cpp] + redx[192 + cpp];
    g[t] = sum * scale[t] + (float)(e - s) * shift[t];
  }
  __syncthreads();
  if (t < 128) {
    float a2 = bp[t];
#pragma unroll 8
    for (int k = 0; k < 128; ++k) a2 = fmaf(g[k], Wp[k * 128 + t], a2);
    out[gid * 128 + t] = fmaxf(a2, 0.f);
  }
}

extern "C" void kernel_launch(void* const* d_in, const int* in_sizes, int n_in,
                              void* d_out, int out_size, void* d_ws, size_t ws_size,
                              hipStream_t stream) {
  const float* x = (const float*)d_in[0];
  const int* ei = (const int*)d_in[1];
  const int* batch = (const int*)d_in[2];
  const float* W1 = (const float*)d_in[3];
  const float* b1 = (const float*)d_in[4];
  const float* W2 = (const float*)d_in[5];
  const float* b2 = (const float*)d_in[6];
  const float* gamma = (const float*)d_in[7];
  const float* beta = (const float*)d_in[8];
  const float* Wp = (const float*)d_in[9];
  const float* bp = (const float*)d_in[10];
  float* out = (float*)d_out;

  int M = in_sizes[0] / 128;
  int E = in_sizes[1] / 2;
  int L = in_sizes[3] / (128 * 128);
  int G = out_size / 128;
  const int* srcp = ei;
  const int* dstp = ei + E;

  char* w = (char*)d_ws;
  auto alloc = [&](size_t bytes) {
    char* p = w;
    w += (bytes + 255) & ~(size_t)255;
    return p;
  };
  int nblk = (M + 31) / 32;
  int CB = (M + 511) >> 9;  // coarse buckets (512 rows each), <=128
  unsigned int* bufA = (unsigned int*)alloc((size_t)M * 64 * 4);
  unsigned int* bufB = (unsigned int*)alloc((size_t)M * 64 * 4);
  unsigned short* WT = (unsigned short*)alloc((size_t)L * 2 * 16384 * 2);
  int* counts = (int*)alloc((size_t)M * 4);
  int* incl = (int*)alloc((size_t)M * 4);
  int* bsums = (int*)alloc(1024 * 4);
  int* offsets = (int*)alloc((size_t)(M + 1) * 4);
  int* cursor = (int*)alloc((size_t)M * 4);
  int* ccursor = (int*)alloc(128 * 4);
  unsigned int* tmp = (unsigned int*)alloc((size_t)E * 4);
  unsigned short* srcs = (unsigned short*)alloc((size_t)E * 2);
  float* pstat = (float*)alloc((size_t)nblk * 256 * 4);
  float* stats = (float*)alloc(2 * 128 * 4);
  float* scale = stats;
  float* shift = stats + 128;

  int nb1 = (M + 1023) / 1024;

  prep_kernel<<<2048, 256, 0, stream>>>(x, bufA, counts, scale, shift, M);
  hist_kernel<<<(E + 255) / 256, 256, 0, stream>>>(dstp, counts, E);
  scan1_kernel<<<nb1, 1024, 0, stream>>>(counts, incl, bsums, M);
  scan2_kernel<<<1, 1024, 0, stream>>>(bsums, nb1);
  scan3_kernel<<<(M + 255) / 256, 256, 0, stream>>>(counts, incl, bsums, offsets, cursor,
                                                    ccursor, M);
  sortA_kernel<<<(E + EPB - 1) / EPB, 256, 0, stream>>>(srcp, dstp, ccursor, tmp, E, CB);
  sortB_kernel<<<CB * 4, 256, 0, stream>>>(tmp, offsets, cursor, srcs, M);
  prep_w_kernel<<<(L * 2 * 16384 + 255) / 256, 256, 0, stream>>>(W1, W2, WT, L * 2 * 16384);

  float invM = 1.0f / (float)M;
  unsigned int* cur = bufA;
  unsigned int* nxt = bufB;
  for (int l = 0; l < L; ++l) {
    layer_kernel<<<nblk, 512, 0, stream>>>(
        cur, offsets, srcs, scale, shift, WT + (size_t)(2 * l) * 16384, b1 + l * 128,
        WT + (size_t)(2 * l + 1) * 16384, b2 + l * 128, (unsigned short*)nxt, pstat, M);
    bn_stats_kernel<<<128, 256, 0, stream>>>(pstat, nblk, gamma + l * 128, beta + l * 128,
                                             scale, shift, invM);
    unsigned int* tmpp = cur; cur = nxt; nxt = tmpp;
  }

  pool_proj_kernel<<<G, 256, 0, stream>>>(cur, batch, scale, shift, Wp, bp, out, M);
}

// Round 13
// 356.512 us; speedup vs baseline: 1.1965x; 1.1127x over previous
//
#include <hip/hip_runtime.h>

// ---------------------------------------------------------------------------
// GIN encoder, fp16 feature path + MFMA, fused per-layer kernel (512 thr).
// Gather floor (rounds 6-12 ablations): compulsory per-XCD re-fetch of H
// (~80 MB/layer FETCH) at the ~1.26 TB/s random-256B-row fill rate => ~70
// us/layer; insensitive to issue rate, latency depth, L1 policy, phasing,
// sorting. This round collapses CSR-build overhead:
//   prep_fused: x->fp16 + W->WT + affine init + LDS-staged coarse hist
//               (392 blocks write per-block 128-bin partials, no atomics)
//   cscan (1 blk): sum partials + scan 128 buckets -> ccursor/cbase
//   sortA: coarse sort into 512-row buckets (round-12, validated)
//   sortB: per-bucket LDS counting sort -> writes offsets[] AND srcs[]
// Layer kernel / bn_stats / pool_proj byte-identical to round 12.
// ---------------------------------------------------------------------------

typedef __attribute__((ext_vector_type(8))) _Float16 f16x8;
typedef __attribute__((ext_vector_type(4))) float f32x4;

static __device__ __forceinline__ float h2f(unsigned short u) {
  return (float)__builtin_bit_cast(_Float16, u);
}
static __device__ __forceinline__ unsigned short f2h(float f) {
  return __builtin_bit_cast(unsigned short, (_Float16)f);
}
static __device__ __forceinline__ float lo16(unsigned int v) { return h2f((unsigned short)(v & 0xffffu)); }
static __device__ __forceinline__ float hi16(unsigned int v) { return h2f((unsigned short)(v >> 16)); }

#define HB 392  // blocks participating in the coarse histogram

// ---- fused prep: x->fp16, W->WT, affine init, coarse dst-hist partials ----
__global__ __launch_bounds__(256) void prep_fused_kernel(
    const float* __restrict__ x, unsigned int* __restrict__ h,
    const float* __restrict__ W1, const float* __restrict__ W2,
    unsigned short* __restrict__ WT, const int* __restrict__ dst,
    int* __restrict__ partial, float* __restrict__ scale, float* __restrict__ shift,
    int M, int E, int Ltot) {
  __shared__ int hcnt[128];
  int t = threadIdx.x;
  int tid = blockIdx.x * 256 + t;
  int stride = gridDim.x * 256;
  bool doHist = (blockIdx.x < HB);
  if (doHist) {
    if (t < 128) hcnt[t] = 0;
    __syncthreads();
    for (int e = blockIdx.x * 256 + t; e < E; e += HB * 256)
      atomicAdd(&hcnt[dst[e] >> 9], 1);
  }
  // x -> fp16 packed
  const float2* x2 = (const float2*)x;
  int total = M * 64;
  for (int i = tid; i < total; i += stride) {
    float2 v = x2[i];
    h[i] = (unsigned int)f2h(v.x) | ((unsigned int)f2h(v.y) << 16);
  }
  // W -> WT (transposed fp16): WT[m][n][k] = f16(W_m[k][n])
  int wtotal = Ltot * 2 * 16384;
  for (int idx = tid; idx < wtotal; idx += stride) {
    int m = idx >> 14;
    int rem = idx & 16383;
    int n = rem >> 7, k = rem & 127;
    const float* W = ((m & 1) == 0) ? (W1 + (size_t)(m >> 1) * 16384)
                                    : (W2 + (size_t)(m >> 1) * 16384);
    WT[idx] = f2h(W[k * 128 + n]);
  }
  if (tid < 128) { scale[tid] = 1.f; shift[tid] = 0.f; }
  if (doHist) {
    __syncthreads();
    if (t < 128) partial[blockIdx.x * 128 + t] = hcnt[t];
  }
}

// ---- sum partials + exclusive scan of 128 coarse buckets ----
__global__ __launch_bounds__(128) void cscan_kernel(const int* __restrict__ partial,
                                                    int* __restrict__ ccursor,
                                                    int* __restrict__ cbase, int E) {
  __shared__ int buf[2][128];
  int t = threadIdx.x;
  int s = 0;
  for (int k = 0; k < HB; ++k) s += partial[k * 128 + t];
  buf[0][t] = s;
  __syncthreads();
  int cur = 0;
  for (int off = 1; off < 128; off <<= 1) {
    buf[cur ^ 1][t] = buf[cur][t] + ((t >= off) ? buf[cur][t - off] : 0);
    __syncthreads();
    cur ^= 1;
  }
  int excl = buf[cur][t] - s;
  ccursor[t] = excl;
  cbase[t] = excl;
  if (t == 127) cbase[128] = E;
}

// ---- passA: coarse sort edges into 512-row buckets; packed v=(d<<16)|s ----
#define EPB 4096
__global__ __launch_bounds__(256) void sortA_kernel(const int* __restrict__ src,
                                                    const int* __restrict__ dst,
                                                    int* __restrict__ ccursor,
                                                    unsigned int* __restrict__ tmp, int E) {
  __shared__ int cnt[128], pref[128], gbase[128];
  __shared__ int scanbuf[2][128];
  __shared__ unsigned int vals[EPB];
  int t = threadIdx.x;
  int base = blockIdx.x * EPB;
  int nloc = min(EPB, E - base);
  if (t < 128) cnt[t] = 0;
  __syncthreads();

  unsigned int vj[16];
  int rj[16];
#pragma unroll
  for (int j = 0; j < 16; ++j) {
    int e = base + j * 256 + t;
    vj[j] = 0u;
    rj[j] = -1;
    if (e < base + nloc) {
      int s = src[e], d = dst[e];
      unsigned int v = ((unsigned int)d << 16) | (unsigned int)s;
      vj[j] = v;
      rj[j] = atomicAdd(&cnt[v >> 25], 1);
    }
  }
  __syncthreads();
  if (t < 128) scanbuf[0][t] = cnt[t];
  __syncthreads();
  int cur = 0;
  for (int off = 1; off < 128; off <<= 1) {
    if (t < 128) scanbuf[cur ^ 1][t] = scanbuf[cur][t] + ((t >= off) ? scanbuf[cur][t - off] : 0);
    __syncthreads();
    cur ^= 1;
  }
  if (t < 128) pref[t] = scanbuf[cur][t] - cnt[t];
  __syncthreads();
  if (t < 128 && cnt[t] > 0) gbase[t] = atomicAdd(&ccursor[t], cnt[t]);
  __syncthreads();
#pragma unroll
  for (int j = 0; j < 16; ++j) {
    if (rj[j] >= 0) vals[pref[vj[j] >> 25] + rj[j]] = vj[j];
  }
  __syncthreads();
  for (int j = t; j < nloc; j += 256) {
    unsigned int v = vals[j];
    int b = v >> 25;
    tmp[gbase[b] + (j - pref[b])] = v;
  }
}

// ---- passB: per-bucket LDS counting sort -> offsets[] + srcs[] ----
__global__ __launch_bounds__(512) void sortB_kernel(const unsigned int* __restrict__ tmp,
                                                    const int* __restrict__ cbase,
                                                    int* __restrict__ offsets,
                                                    unsigned short* __restrict__ srcs,
                                                    int M, int E) {
  __shared__ int lcnt[512];
  __shared__ int sbuf[2][512];
  int b = blockIdx.x;
  int t = threadIdx.x;
  int e0 = cbase[b], e1 = cbase[b + 1];
  int r0 = b << 9;
  lcnt[t] = 0;
  __syncthreads();
  for (int e = e0 + t; e < e1; e += 512) atomicAdd(&lcnt[(tmp[e] >> 16) & 511], 1);
  __syncthreads();
  sbuf[0][t] = lcnt[t];
  __syncthreads();
  int cur = 0;
  for (int off = 1; off < 512; off <<= 1) {
    sbuf[cur ^ 1][t] = sbuf[cur][t] + ((t >= off) ? sbuf[cur][t - off] : 0);
    __syncthreads();
    cur ^= 1;
  }
  int excl = sbuf[cur][t] - lcnt[t];
  int r = r0 + t;
  if (r < M) offsets[r] = e0 + excl;
  if (r == M - 1) offsets[M] = E;
  __syncthreads();
  lcnt[t] = e0 + excl;  // running global cursor per row
  __syncthreads();
  for (int e = e0 + t; e < e1; e += 512) {
    unsigned int v = tmp[e];
    int p = atomicAdd(&lcnt[(v >> 16) & 511], 1);
    srcs[p] = (unsigned short)(v & 0xffffu);
  }
}

// ---- fused layer: gather+BN -> LDS -> GEMM1 -> LDS -> GEMM2 -> Hout+stats ----
// 32-row tile, 8 waves; each wave gathers 4 rows (2 in flight, unroll-4).
// LDS tile swizzle: fp16 col c of row rl at byte (rl*256 + ((c*2) ^ ((rl&7)<<4))).
// MFMA frag layouts (m89-verified, rounds 3-12).
__global__ __launch_bounds__(512, 8) void layer_kernel(
    const unsigned int* __restrict__ Hin,  // M x 64 uints (fp16x2, row-major)
    const int* __restrict__ offsets,       // M + 1
    const unsigned short* __restrict__ srcs,
    const float* __restrict__ scale, const float* __restrict__ shift,
    const unsigned short* __restrict__ WT1, const float* __restrict__ b1,
    const unsigned short* __restrict__ WT2, const float* __restrict__ b2,
    unsigned short* __restrict__ Hout,  // M x 128 fp16 row-major
    float* __restrict__ pstat, int M) {
  __shared__ unsigned short sT[32 * 128];
  __shared__ float s_sum[128], s_sq[128];
  int t = threadIdx.x;
  if (t < 128) { s_sum[t] = 0.f; s_sq[t] = 0.f; }
  int wave = t >> 6, lane = t & 63;
  int row0 = blockIdx.x * 32;
  char* sTb = (char*)sT;
  float sc0 = scale[2 * lane], sc1 = scale[2 * lane + 1];
  float sh0 = shift[2 * lane], sh1 = shift[2 * lane + 1];

  for (int i = 0; i < 4; i += 2) {
    int rA = row0 + wave * 4 + i;
    int rB = rA + 1;
    float axA = 0.f, ayA = 0.f, axB = 0.f, ayB = 0.f;
    int eA = 0, eA1 = 0, eB = 0, eB1 = 0;
    if (rA < M) {
      eA = offsets[rA]; eA1 = offsets[rA + 1];
      unsigned int s = Hin[(size_t)rA * 64 + lane];
      axA = lo16(s); ayA = hi16(s);
    }
    if (rB < M) {
      eB = offsets[rB]; eB1 = offsets[rB + 1];
      unsigned int s = Hin[(size_t)rB * 64 + lane];
      axB = lo16(s); ayB = hi16(s);
    }
    int dA = eA1 - eA, dB = eB1 - eB;
    while (eA + 4 <= eA1 && eB + 4 <= eB1) {
      int a0 = srcs[eA], a1 = srcs[eA + 1], a2 = srcs[eA + 2], a3 = srcs[eA + 3];
      int c0 = srcs[eB], c1 = srcs[eB + 1], c2 = srcs[eB + 2], c3 = srcs[eB + 3];
      unsigned int vA0 = Hin[(size_t)a0 * 64 + lane];
      unsigned int vA1 = Hin[(size_t)a1 * 64 + lane];
      unsigned int vA2 = Hin[(size_t)a2 * 64 + lane];
      unsigned int vA3 = Hin[(size_t)a3 * 64 + lane];
      unsigned int vB0 = Hin[(size_t)c0 * 64 + lane];
      unsigned int vB1 = Hin[(size_t)c1 * 64 + lane];
      unsigned int vB2 = Hin[(size_t)c2 * 64 + lane];
      unsigned int vB3 = Hin[(size_t)c3 * 64 + lane];
      axA += lo16(vA0) + lo16(vA1) + lo16(vA2) + lo16(vA3);
      ayA += hi16(vA0) + hi16(vA1) + hi16(vA2) + hi16(vA3);
      axB += lo16(vB0) + lo16(vB1) + lo16(vB2) + lo16(vB3);
      ayB += hi16(vB0) + hi16(vB1) + hi16(vB2) + hi16(vB3);
      eA += 4; eB += 4;
    }
    while (eA + 4 <= eA1) {
      int a0 = srcs[eA], a1 = srcs[eA + 1], a2 = srcs[eA + 2], a3 = srcs[eA + 3];
      unsigned int v0 = Hin[(size_t)a0 * 64 + lane];
      unsigned int v1 = Hin[(size_t)a1 * 64 + lane];
      unsigned int v2 = Hin[(size_t)a2 * 64 + lane];
      unsigned int v3 = Hin[(size_t)a3 * 64 + lane];
      axA += lo16(v0) + lo16(v1) + lo16(v2) + lo16(v3);
      ayA += hi16(v0) + hi16(v1) + hi16(v2) + hi16(v3);
      eA += 4;
    }
    while (eB + 4 <= eB1) {
      int c0 = srcs[eB], c1 = srcs[eB + 1], c2 = srcs[eB + 2], c3 = srcs[eB + 3];
      unsigned int v0 = Hin[(size_t)c0 * 64 + lane];
      unsigned int v1 = Hin[(size_t)c1 * 64 + lane];
      unsigned int v2 = Hin[(size_t)c2 * 64 + lane];
      unsigned int v3 = Hin[(size_t)c3 * 64 + lane];
      axB += lo16(v0) + lo16(v1) + lo16(v2) + lo16(v3);
      ayB += hi16(v0) + hi16(v1) + hi16(v2) + hi16(v3);
      eB += 4;
    }
    for (; eA < eA1; ++eA) {
      unsigned int v = Hin[(size_t)srcs[eA] * 64 + lane];
      axA += lo16(v); ayA += hi16(v);
    }
    for (; eB < eB1; ++eB) {
      unsigned int v = Hin[(size_t)srcs[eB] * 64 + lane];
      axB += lo16(v); ayB += hi16(v);
    }
    int rlA = wave * 4 + i, rlB = rlA + 1;
    float dA1 = (float)(dA + 1), dB1 = (float)(dB + 1);
    unsigned int oA = (unsigned int)f2h(axA * sc0 + dA1 * sh0) |
                      ((unsigned int)f2h(ayA * sc1 + dA1 * sh1) << 16);
    unsigned int oB = (unsigned int)f2h(axB * sc0 + dB1 * sh0) |
                      ((unsigned int)f2h(ayB * sc1 + dB1 * sh1) << 16);
    *(unsigned int*)(sTb + rlA * 256 + ((lane * 4) ^ ((rlA & 7) << 4))) = (rA < M) ? oA : 0u;
    *(unsigned int*)(sTb + rlB * 256 + ((lane * 4) ^ ((rlB & 7) << 4))) = (rB < M) ? oB : 0u;
  }
  __syncthreads();

  int wr = wave & 1, wc = wave >> 1;
  int lrow = lane & 15, hi = lane >> 4;
  int lk = hi * 8;
  int rl = wr * 16 + lrow;

  // GEMM1
  f16x8 af[4];
#pragma unroll
  for (int ks = 0; ks < 4; ++ks)
    af[ks] = *(const f16x8*)(sTb + rl * 256 + ((ks * 64 + hi * 16) ^ ((rl & 7) << 4)));
  f32x4 acc[2];
#pragma unroll
  for (int n = 0; n < 2; ++n) acc[n] = (f32x4){0.f, 0.f, 0.f, 0.f};
#pragma unroll
  for (int ks = 0; ks < 4; ++ks) {
    f16x8 bf[2];
#pragma unroll
    for (int n = 0; n < 2; ++n)
      bf[n] = *(const f16x8*)(WT1 + (size_t)(wc * 32 + n * 16 + lrow) * 128 + ks * 32 + lk);
#pragma unroll
    for (int n = 0; n < 2; ++n)
      acc[n] = __builtin_amdgcn_mfma_f32_16x16x32_f16(af[ks], bf[n], acc[n], 0, 0, 0);
  }
  __syncthreads();

#pragma unroll
  for (int n = 0; n < 2; ++n) {
    int col = wc * 32 + n * 16 + lrow;
    float bia = b1[col];
#pragma unroll
    for (int r = 0; r < 4; ++r) {
      int rlw = wr * 16 + hi * 4 + r;
      float v = fmaxf(acc[n][r] + bia, 0.f);
      *(unsigned short*)(sTb + rlw * 256 + ((col * 2) ^ ((rlw & 7) << 4))) = f2h(v);
    }
  }
  __syncthreads();

  // GEMM2
#pragma unroll
  for (int ks = 0; ks < 4; ++ks)
    af[ks] = *(const f16x8*)(sTb + rl * 256 + ((ks * 64 + hi * 16) ^ ((rl & 7) << 4)));
#pragma unroll
  for (int n = 0; n < 2; ++n) acc[n] = (f32x4){0.f, 0.f, 0.f, 0.f};
#pragma unroll
  for (int ks = 0; ks < 4; ++ks) {
    f16x8 bf[2];
#pragma unroll
    for (int n = 0; n < 2; ++n)
      bf[n] = *(const f16x8*)(WT2 + (size_t)(wc * 32 + n * 16 + lrow) * 128 + ks * 32 + lk);
#pragma unroll
    for (int n = 0; n < 2; ++n)
      acc[n] = __builtin_amdgcn_mfma_f32_16x16x32_f16(af[ks], bf[n], acc[n], 0, 0, 0);
  }

  int rbase = row0 + wr * 16 + hi * 4;
#pragma unroll
  for (int n = 0; n < 2; ++n) {
    int col = wc * 32 + n * 16 + lrow;
    float bia = b2[col];
    float cs = 0.f, cq = 0.f;
#pragma unroll
    for (int r = 0; r < 4; ++r) {
      int rr = rbase + r;
      float v = fmaxf(acc[n][r] + bia, 0.f);
      if (rr < M) {
        Hout[(size_t)rr * 128 + col] = f2h(v);
        cs += v;
        cq += v * v;
      }
    }
    cs += __shfl_xor(cs, 16); cs += __shfl_xor(cs, 32);
    cq += __shfl_xor(cq, 16); cq += __shfl_xor(cq, 32);
    if (hi == 0) {
      atomicAdd(&s_sum[col], cs);
      atomicAdd(&s_sq[col], cq);
    }
  }
  __syncthreads();
  if (t < 128) {
    float* p = pstat + (size_t)blockIdx.x * 256;
    p[t] = s_sum[t];
    p[t + 128] = s_sq[t];
  }
}

// reduce per-block partials -> scale/shift for the next layer
__global__ __launch_bounds__(256) void bn_stats_kernel(const float* __restrict__ pstat, int nb,
                                                       const float* __restrict__ gamma,
                                                       const float* __restrict__ beta,
                                                       float* __restrict__ scale,
                                                       float* __restrict__ shift, float invM) {
  int c = blockIdx.x;
  int t = threadIdx.x;
  float s = 0.f, q = 0.f;
  for (int b = t; b < nb; b += 256) {
    const float* p = pstat + (size_t)b * 256;
    s += p[c];
    q += p[c + 128];
  }
#pragma unroll
  for (int off = 1; off < 64; off <<= 1) {
    s += __shfl_xor(s, off);
    q += __shfl_xor(q, off);
  }
  __shared__ float rs[4], rq[4];
  if ((t & 63) == 0) { rs[t >> 6] = s; rq[t >> 6] = q; }
  __syncthreads();
  if (t == 0) {
    float S = rs[0] + rs[1] + rs[2] + rs[3];
    float Q = rq[0] + rq[1] + rq[2] + rq[3];
    float mean = S * invM;
    float var = fmaxf(Q * invM - mean * mean, 0.f);
    float sc = gamma[c] * rsqrtf(var + 1e-5f);
    scale[c] = sc;
    shift[c] = beta[c] - mean * sc;
  }
}

// ---- fused pool (last layer BN) + projection ----
__global__ __launch_bounds__(256) void pool_proj_kernel(const unsigned int* __restrict__ H,
                                                        const int* __restrict__ batch,
                                                        const float* __restrict__ scale,
                                                        const float* __restrict__ shift,
                                                        const float* __restrict__ Wp,
                                                        const float* __restrict__ bp,
                                                        float* __restrict__ out, int M) {
  int gid = blockIdx.x;
  int lo = 0, hi = M;
  while (lo < hi) { int mid = (lo + hi) >> 1; if (batch[mid] < gid) lo = mid + 1; else hi = mid; }
  int s = lo;
  lo = 0; hi = M;
  while (lo < hi) { int mid = (lo + hi) >> 1; if (batch[mid] < gid + 1) lo = mid + 1; else hi = mid; }
  int e = lo;
  int t = threadIdx.x;
  int cp = t & 63, rs_ = t >> 6;
  float ax = 0.f, ay = 0.f;
  for (int r = s + rs_; r < e; r += 4) {
    unsigned int v = H[(size_t)r * 64 + cp];
    ax += lo16(v);
    ay += hi16(v);
  }
  __shared__ float redx[256], redy[256];
  __shared__ float g[128];
  redx[t] = ax;
  redy[t] = ay;
  __syncthreads();
  if (t < 128) {
    int cpp = t >> 1;
    float sum;
    if (t & 1)
      sum = redy[cpp] + redy[64 + cpp] + redy[128 + cpp] + redy[192 + cpp];
    else
      sum = redx[cpp] + redx[64 + cpp] + redx[128 + cpp] + redx[192 + cpp];
    g[t] = sum * scale[t] + (float)(e - s) * shift[t];
  }
  __syncthreads();
  if (t < 128) {
    float a2 = bp[t];
#pragma unroll 8
    for (int k = 0; k < 128; ++k) a2 = fmaf(g[k], Wp[k * 128 + t], a2);
    out[gid * 128 + t] = fmaxf(a2, 0.f);
  }
}

extern "C" void kernel_launch(void* const* d_in, const int* in_sizes, int n_in,
                              void* d_out, int out_size, void* d_ws, size_t ws_size,
                              hipStream_t stream) {
  const float* x = (const float*)d_in[0];
  const int* ei = (const int*)d_in[1];
  const int* batch = (const int*)d_in[2];
  const float* W1 = (const float*)d_in[3];
  const float* b1 = (const float*)d_in[4];
  const float* W2 = (const float*)d_in[5];
  const float* b2 = (const float*)d_in[6];
  const float* gamma = (const float*)d_in[7];
  const float* beta = (const float*)d_in[8];
  const float* Wp = (const float*)d_in[9];
  const float* bp = (const float*)d_in[10];
  float* out = (float*)d_out;

  int M = in_sizes[0] / 128;
  int E = in_sizes[1] / 2;
  int L = in_sizes[3] / (128 * 128);
  int G = out_size / 128;
  const int* srcp = ei;
  const int* dstp = ei + E;

  char* w = (char*)d_ws;
  auto alloc = [&](size_t bytes) {
    char* p = w;
    w += (bytes + 255) & ~(size_t)255;
    return p;
  };
  int nblk = (M + 31) / 32;
  int CB = (M + 511) >> 9;  // coarse buckets (512 rows each), <=128
  unsigned int* bufA = (unsigned int*)alloc((size_t)M * 64 * 4);
  unsigned int* bufB = (unsigned int*)alloc((size_t)M * 64 * 4);
  unsigned short* WT = (unsigned short*)alloc((size_t)L * 2 * 16384 * 2);
  int* partial = (int*)alloc((size_t)HB * 128 * 4);
  int* ccursor = (int*)alloc(128 * 4);
  int* cbase = (int*)alloc(132 * 4);
  int* offsets = (int*)alloc((size_t)(M + 1) * 4);
  unsigned int* tmp = (unsigned int*)alloc((size_t)E * 4);
  unsigned short* srcs = (unsigned short*)alloc((size_t)E * 2);
  float* pstat = (float*)alloc((size_t)nblk * 256 * 4);
  float* stats = (float*)alloc(2 * 128 * 4);
  float* scale = stats;
  float* shift = stats + 128;

  prep_fused_kernel<<<2048, 256, 0, stream>>>(x, bufA, W1, W2, WT, dstp, partial, scale, shift,
                                              M, E, L);
  cscan_kernel<<<1, 128, 0, stream>>>(partial, ccursor, cbase, E);
  sortA_kernel<<<(E + EPB - 1) / EPB, 256, 0, stream>>>(srcp, dstp, ccursor, tmp, E);
  sortB_kernel<<<CB, 512, 0, stream>>>(tmp, cbase, offsets, srcs, M, E);

  float invM = 1.0f / (float)M;
  unsigned int* cur = bufA;
  unsigned int* nxt = bufB;
  for (int l = 0; l < L; ++l) {
    layer_kernel<<<nblk, 512, 0, stream>>>(
        cur, offsets, srcs, scale, shift, WT + (size_t)(2 * l) * 16384, b1 + l * 128,
        WT + (size_t)(2 * l + 1) * 16384, b2 + l * 128, (unsigned short*)nxt, pstat, M);
    bn_stats_kernel<<<128, 256, 0, stream>>>(pstat, nblk, gamma + l * 128, beta + l * 128,
                                             scale, shift, invM);
    unsigned int* tmpp = cur; cur = nxt; nxt = tmpp;
  }

  pool_proj_kernel<<<G, 256, 0, stream>>>(cur, batch, scale, shift, Wp, bp, out, M);
}